// Round 6
// baseline (25.639 us; speedup 1.0000x reference)
//
#include <hip/hip_runtime.h>

// EquivariantProductBasisBlock (MACE symmetric contraction, nu=3) on gfx950.
//
// GEMM form via mfma(coef_frag, mono_frag): D[pc][ch], lane holds ch=lane&31,
// path-cols rr=(r&3)+8*(r>>2)+4*ks across regs (verified R5, absmax 0.0625).
// R6 changes: (1) no LDS staging of coef table -- fragments read directly from
// global (14 KB, L2-broadcast across all 4096 waves); kills the block-entry
// vmcnt-drain + barrier. (2) constexpr decode tables in the build kernel.
// (3) per-element path-weight loads issued before k_steps (latency hiding).

typedef __attribute__((ext_vector_type(8))) short short8;
typedef __attribute__((ext_vector_type(16))) float f32x16;

#define NSTEP 14
#define TBLB_DWORDS (NSTEP*64*4)    // 3584 dwords: Coef frags (A-side)
#define WL_OFF TBLB_DWORDS
#define TBLW_DWORDS (64*256)        // 16384 dwords: Wlin B-frags

static __device__ __forceinline__ short bf16b(float f) {
  __bf16 h = (__bf16)f;
  return __builtin_bit_cast(short, h);
}

// ---- compile-time monomial index table (lex order) ----
struct Triples { unsigned char a[224], b[224], c3[224], ord[224]; };
constexpr Triples make_triples() {
  Triples T{};
  int s = 0;
  for (int i = 0; i < 9; ++i)
    for (int j = i; j < 9; ++j)
      for (int k = j; k < 9; ++k) { T.a[s]=(unsigned char)i; T.b[s]=(unsigned char)j; T.c3[s]=(unsigned char)k; T.ord[s]=3; ++s; }
  for (int i = 0; i < 9; ++i)
    for (int j = i; j < 9; ++j) { T.a[s]=(unsigned char)i; T.b[s]=(unsigned char)j; T.ord[s]=2; ++s; }
  for (int i = 0; i < 9; ++i) { T.a[s]=(unsigned char)i; T.ord[s]=1; ++s; }
  for (; s < 224; ++s) T.ord[s] = 0;
  return T;
}
static constexpr Triples TRI = make_triples();

// ---- compile-time decode tables for the build kernel ----
struct DecTab {
  unsigned short b3[165][6]; unsigned char c3[165];
  unsigned short b2[45][2];  unsigned char c2[45];
};
constexpr DecTab make_dectab() {
  DecTab D{};
  int s = 0;
  for (int i = 0; i < 9; ++i)
    for (int j = i; j < 9; ++j)
      for (int k = j; k < 9; ++k) {
        int pm[6][3] = {{i,j,k},{i,k,j},{j,i,k},{j,k,i},{k,i,j},{k,j,i}};
        int cnt = 0;
        for (int q = 0; q < 6; ++q) {
          bool dup = false;
          for (int r = 0; r < q; ++r)
            if (pm[r][0]==pm[q][0] && pm[r][1]==pm[q][1] && pm[r][2]==pm[q][2]) dup = true;
          if (!dup) { D.b3[s][cnt] = (unsigned short)((pm[q][0]*9 + pm[q][1])*9 + pm[q][2]); ++cnt; }
        }
        D.c3[s] = (unsigned char)cnt; ++s;
      }
  s = 0;
  for (int i = 0; i < 9; ++i)
    for (int j = i; j < 9; ++j) {
      D.b2[s][0] = (unsigned short)(i*9 + j);
      D.b2[s][1] = (unsigned short)(j*9 + i);
      D.c2[s] = (unsigned char)((i == j) ? 1 : 2); ++s;
    }
  return D;
}
static constexpr DecTab DT = make_dectab();

template<int KI>
static __device__ __forceinline__ float monoT(const float* xr) {
  if constexpr (TRI.ord[KI] == 3) return xr[TRI.a[KI]] * xr[TRI.b[KI]] * xr[TRI.c3[KI]];
  else if constexpr (TRI.ord[KI] == 2) return xr[TRI.a[KI]] * xr[TRI.b[KI]];
  else if constexpr (TRI.ord[KI] == 1) return xr[TRI.a[KI]];
  else return 0.f;
}

template<int K0>
static __device__ __forceinline__ void mono8(const float* xr, float m[8]) {
  m[0]=monoT<K0+0>(xr); m[1]=monoT<K0+1>(xr); m[2]=monoT<K0+2>(xr); m[3]=monoT<K0+3>(xr);
  m[4]=monoT<K0+4>(xr); m[5]=monoT<K0+5>(xr); m[6]=monoT<K0+6>(xr); m[7]=monoT<K0+7>(xr);
}

template<int T>
static __device__ __forceinline__ void k_steps(const float* xr, const unsigned int* __restrict__ tbl,
                                               int lane, int ks, f32x16& acc) {
  if constexpr (T < NSTEP) {
    float m[8];
    if (ks == 0) mono8<T*16>(xr, m);
    else         mono8<T*16 + 8>(xr, m);
    short8 mf;
    mf[0]=bf16b(m[0]); mf[1]=bf16b(m[1]); mf[2]=bf16b(m[2]); mf[3]=bf16b(m[3]);
    mf[4]=bf16b(m[4]); mf[5]=bf16b(m[5]); mf[6]=bf16b(m[6]); mf[7]=bf16b(m[7]);
    short8 cf = *(const short8*)&tbl[(T*64 + lane)*4];   // global, L2-broadcast
    acc = __builtin_amdgcn_mfma_f32_32x32x16_bf16(cf, mf, acc, 0, 0, 0);
    k_steps<T+1>(xr, tbl, lane, ks, acc);
  }
}

// ---- build kernel ----
static __device__ __forceinline__ float coefval(int k, int col,
    const float* U1_0, const float* U2_0, const float* U3_0,
    const float* U1_1, const float* U2_1, const float* U3_1) {
  if (k < 165) {
    if (col < 12 || col >= 24) return 0.f;
    int mp = (col - 12) / 3, p = (col - 12) % 3;
    float acc = 0.f;
    int cnt = DT.c3[k];
    for (int q = 0; q < cnt; ++q) {
      int base = DT.b3[k][q];
      acc += (mp == 0) ? U3_0[base*3 + p] : U3_1[base*9 + (mp-1)*3 + p];
    }
    return acc;
  } else if (k < 210) {
    if (col < 4 || col >= 12) return 0.f;
    int mp = (col - 4) / 2, p = (col - 4) % 2;
    int s2 = k - 165;
    float acc = 0.f;
    int cnt = DT.c2[s2];
    for (int q = 0; q < cnt; ++q) {
      int base = DT.b2[s2][q];
      acc += (mp == 0) ? U2_0[base*2 + p] : U2_1[(base*3 + (mp-1))*2 + p];
    }
    return acc;
  } else if (k < 219) {
    int i = k - 210;
    if (col == 0) return U1_0[i];
    if (col < 4) return U1_1[i*3 + (col-1)];
    return 0.f;
  }
  return 0.f;
}

__global__ __launch_bounds__(64) void build_tables_kernel(
    const float* __restrict__ U1_0, const float* __restrict__ U2_0, const float* __restrict__ U3_0,
    const float* __restrict__ U1_1, const float* __restrict__ U2_1, const float* __restrict__ U3_1,
    const float* __restrict__ Wl0, const float* __restrict__ Wl1,
    unsigned int* __restrict__ tbl) {
  const int b = blockIdx.x, l = threadIdx.x;
  const int col = l & 31, ks = l >> 5;
  if (b < NSTEP) {
    const int ft = b;
    #pragma unroll
    for (int d = 0; d < 4; ++d) {
      int k = ft*16 + ks*8 + d*2;
      unsigned short lo = (unsigned short)bf16b(coefval(k,   col, U1_0,U2_0,U3_0,U1_1,U2_1,U3_1));
      unsigned short hi = (unsigned short)bf16b(coefval(k+1, col, U1_0,U2_0,U3_0,U1_1,U2_1,U3_1));
      tbl[(ft*64 + l)*4 + d] = ((unsigned int)hi << 16) | lo;
    }
  } else {
    const int u = b - NSTEP;            // 0..63 : (g, ntile, step)
    const int g = u >> 5, u5 = u & 31, nt = u5 >> 3, st = u5 & 7;
    const float* W = g ? Wl1 : Wl0;     // [c][d] row-major; k = c
    #pragma unroll
    for (int d = 0; d < 4; ++d) {
      int k = st*16 + ks*8 + 2*d;
      unsigned short lo = (unsigned short)bf16b(W[(long)k*128     + nt*32 + col]);
      unsigned short hi = (unsigned short)bf16b(W[(long)(k+1)*128 + nt*32 + col]);
      tbl[WL_OFF + u*256 + l*4 + d] = ((unsigned int)hi << 16) | lo;
    }
  }
}

// ---- main kernel ----
__global__ __launch_bounds__(512, 4) void epbb_mfma_kernel(
    const float* __restrict__ xg,    // [N,128,9]
    const float* __restrict__ na,    // [N,10] one-hot
    const float* __restrict__ sc,    // [N,512]
    const float* __restrict__ W1_0, const float* __restrict__ W2_0, const float* __restrict__ W3_0,
    const float* __restrict__ W1_1, const float* __restrict__ W2_1, const float* __restrict__ W3_1,
    const unsigned int* __restrict__ tbl,
    float* __restrict__ out) {
  __shared__ __align__(16) short lds_yA[2][8][136];          // 4352 B, 272B row stride

  const int tid  = threadIdx.x;
  const int lane = tid & 63;
  const int w    = tid >> 6;          // wave 0..7
  const int ks   = lane >> 5;
  const int n0   = blockIdx.x * 2;

  // this wave: node nw, channels c0..c0+31; lane owns channel cl
  const int nw = w >> 2;
  const int n  = n0 + nw;
  const int c0 = (w & 3) * 32;
  const int cl = c0 + (lane & 31);
  const float* xp = xg + ((long)(n*128 + cl))*9;
  float xr[9];
  #pragma unroll
  for (int q = 0; q < 9; ++q) xr[q] = xp[q];

  // species (exact one-hot, wave-uniform)
  int e = 0;
  #pragma unroll
  for (int q = 0; q < 10; ++q) e = (na[(long)n*10 + q] > 0.5f) ? q : e;

  // issue per-(element,channel) path-weight loads EARLY (hide L2 latency
  // under phase-1 VALU/MFMA)
  const float w10  = W1_0[e*128 + cl];
  const float w20a = W2_0[(e*2+0)*128 + cl], w20b = W2_0[(e*2+1)*128 + cl];
  const float w30a = W3_0[(e*3+0)*128 + cl], w30b = W3_0[(e*3+1)*128 + cl], w30c = W3_0[(e*3+2)*128 + cl];
  const float w11  = W1_1[e*128 + cl];
  const float w21a = W2_1[(e*2+0)*128 + cl], w21b = W2_1[(e*2+1)*128 + cl];
  const float w31a = W3_1[(e*3+0)*128 + cl], w31b = W3_1[(e*3+1)*128 + cl], w31c = W3_1[(e*3+2)*128 + cl];

  f32x16 acc;
  #pragma unroll
  for (int q = 0; q < 16; ++q) acc[q] = 0.f;

  k_steps<0>(xr, tbl, lane, ks, acc);

  // ---- phase 2: in-register weighted path reduction ----
  // D[pc][ch]: lane holds ch=lane&31, path-col rr=(r&3)+8*(r>>2)+4*ks at reg r.
  float p0, p1, p2, p3;
  if (ks == 0) {
    p0 = w10*acc[0];
    p1 = w11*acc[1] + w31b*acc[8]  + w31c*acc[9];
    p2 = w11*acc[2] + w21a*acc[4]  + w21b*acc[5] + w31a*acc[10] + w31b*acc[11];
    p3 = w11*acc[3] + w21a*acc[6]  + w21b*acc[7];
  } else {
    p0 = w20a*acc[0] + w20b*acc[1] + w30a*acc[4] + w30b*acc[5] + w30c*acc[6];
    p1 = w21a*acc[2] + w21b*acc[3] + w31a*acc[7];
    p2 = w31c*acc[8];
    p3 = w31a*acc[9] + w31b*acc[10] + w31c*acc[11];
  }
  const float y0 = p0 + __shfl_xor(p0, 32, 64);
  const float y1 = p1 + __shfl_xor(p1, 32, 64);
  const float y2 = p2 + __shfl_xor(p2, 32, 64);
  const float y3 = p3 + __shfl_xor(p3, 32, 64);

  // stage y (bf16) into padded A-tile: g0 rows {nv}, g1 rows {(mp-1)*2+nv}
  if (ks == 0) {
    lds_yA[0][nw][cl]     = bf16b(y0);       // mp=0
    lds_yA[1][nw][cl]     = bf16b(y1);       // mp=1 -> row nv
  } else {
    lds_yA[1][2 + nw][cl] = bf16b(y2);       // mp=2 -> row 2+nv
    lds_yA[1][4 + nw][cl] = bf16b(y3);       // mp=3 -> row 4+nv
  }
  __syncthreads();

  // ---- phase 3: z = y * Wlin via padded MFMA (wave -> (g, ntile)) ----
  const int g  = w >> 2;
  const int nt = w & 3;
  f32x16 z;
  #pragma unroll
  for (int q = 0; q < 16; ++q) z[q] = 0.f;
  const unsigned int* bw = tbl + WL_OFF + ((g*4 + nt)*8)*256;
  #pragma unroll
  for (int st = 0; st < 8; ++st) {
    short8 af = *(const short8*)&lds_yA[g][lane & 7][st*16 + ks*8];  // rows>=8 wrap: broadcast
    short8 bf = *(const short8*)&bw[st*256 + lane*4];
    z = __builtin_amdgcn_mfma_f32_32x32x16_bf16(af, bf, z, 0, 0, 0);
  }
  const float inv = 0.088388347648318447f;   // 1/sqrt(128)
  const int d = nt*32 + (lane & 31);
  if (g == 0) {
    if (ks == 0) {
      #pragma unroll
      for (int r = 0; r < 2; ++r) {          // row r = nv
        long o = (long)(n0 + r)*512 + d;
        out[o] = z[r]*inv + sc[o];
      }
    }
  } else {
    if (ks == 0) {
      #pragma unroll
      for (int r = 0; r < 4; ++r) {          // rows 0..3: nv=r&1, mp-1=r>>1
        long o = (long)(n0 + (r & 1))*512 + 128 + 3*d + (r >> 1);
        out[o] = z[r]*inv + sc[o];
      }
    } else {
      #pragma unroll
      for (int r = 0; r < 2; ++r) {          // rows 4,5: nv=r, mp-1=2
        long o = (long)(n0 + r)*512 + 128 + 3*d + 2;
        out[o] = z[r]*inv + sc[o];
      }
    }
  }
}

extern "C" void kernel_launch(void* const* d_in, const int* in_sizes, int n_in,
                              void* d_out, int out_size, void* d_ws, size_t ws_size,
                              hipStream_t stream) {
  const float* xg   = (const float*)d_in[0];   // node_feats [N,128,9]
  const float* na   = (const float*)d_in[1];   // node_attrs [N,10]
  const float* sc   = (const float*)d_in[2];   // sc [N,512]
  const float* U1_0 = (const float*)d_in[3];
  const float* W1_0 = (const float*)d_in[4];
  const float* U2_0 = (const float*)d_in[5];
  const float* W2_0 = (const float*)d_in[6];
  const float* U3_0 = (const float*)d_in[7];
  const float* W3_0 = (const float*)d_in[8];
  const float* Wl0  = (const float*)d_in[9];
  const float* U1_1 = (const float*)d_in[10];
  const float* W1_1 = (const float*)d_in[11];
  const float* U2_1 = (const float*)d_in[12];
  const float* W2_1 = (const float*)d_in[13];
  const float* U3_1 = (const float*)d_in[14];
  const float* W3_1 = (const float*)d_in[15];
  const float* Wl1  = (const float*)d_in[16];

  unsigned int* tbl = (unsigned int*)d_ws;     // (3584 + 16384) dwords = 79872 B
  const int N = in_sizes[0] / (128 * 9);

  hipLaunchKernelGGL(build_tables_kernel, dim3(NSTEP + 64), dim3(64), 0, stream,
                     U1_0, U2_0, U3_0, U1_1, U2_1, U3_1, Wl0, Wl1, tbl);
  hipLaunchKernelGGL(epbb_mfma_kernel, dim3(N/2), dim3(512), 0, stream,
                     xg, na, sc, W1_0, W2_0, W3_0, W1_1, W2_1, W3_1, tbl,
                     (float*)d_out);
}

// Round 7
// 25.363 us; speedup vs baseline: 1.0109x; 1.0109x over previous
//
#include <hip/hip_runtime.h>

// EquivariantProductBasisBlock (MACE symmetric contraction, nu=3) on gfx950.
//
// GEMM form via mfma(coef_frag, mono_frag): D[pc][ch], lane holds ch=lane&31,
// path-cols rr=(r&3)+8*(r>>2)+4*ks across regs (verified R5, absmax 0.0625).
// R7: revert to LDS-staged coef (R5 best); add coalesced x-staging via LDS
// (kills 36B-stride scalar gathers, ~324 line-transactions/wave) and a
// coalesced float4 epilogue through lds_out (kills stride-3 scattered
// stores + sc gathers). Build kernel uses constexpr decode tables.

typedef __attribute__((ext_vector_type(8))) short short8;
typedef __attribute__((ext_vector_type(16))) float f32x16;

#define NSTEP 14
#define TBLB_DWORDS (NSTEP*64*4)    // 3584 dwords: Coef frags (A-side)
#define WL_OFF TBLB_DWORDS
#define TBLW_DWORDS (64*256)        // 16384 dwords: Wlin B-frags

static __device__ __forceinline__ short bf16b(float f) {
  __bf16 h = (__bf16)f;
  return __builtin_bit_cast(short, h);
}

// ---- compile-time monomial index table (lex order) ----
struct Triples { unsigned char a[224], b[224], c3[224], ord[224]; };
constexpr Triples make_triples() {
  Triples T{};
  int s = 0;
  for (int i = 0; i < 9; ++i)
    for (int j = i; j < 9; ++j)
      for (int k = j; k < 9; ++k) { T.a[s]=(unsigned char)i; T.b[s]=(unsigned char)j; T.c3[s]=(unsigned char)k; T.ord[s]=3; ++s; }
  for (int i = 0; i < 9; ++i)
    for (int j = i; j < 9; ++j) { T.a[s]=(unsigned char)i; T.b[s]=(unsigned char)j; T.ord[s]=2; ++s; }
  for (int i = 0; i < 9; ++i) { T.a[s]=(unsigned char)i; T.ord[s]=1; ++s; }
  for (; s < 224; ++s) T.ord[s] = 0;
  return T;
}
static constexpr Triples TRI = make_triples();

// ---- compile-time decode tables for the build kernel ----
struct DecTab {
  unsigned short b3[165][6]; unsigned char c3[165];
  unsigned short b2[45][2];  unsigned char c2[45];
};
constexpr DecTab make_dectab() {
  DecTab D{};
  int s = 0;
  for (int i = 0; i < 9; ++i)
    for (int j = i; j < 9; ++j)
      for (int k = j; k < 9; ++k) {
        int pm[6][3] = {{i,j,k},{i,k,j},{j,i,k},{j,k,i},{k,i,j},{k,j,i}};
        int cnt = 0;
        for (int q = 0; q < 6; ++q) {
          bool dup = false;
          for (int r = 0; r < q; ++r)
            if (pm[r][0]==pm[q][0] && pm[r][1]==pm[q][1] && pm[r][2]==pm[q][2]) dup = true;
          if (!dup) { D.b3[s][cnt] = (unsigned short)((pm[q][0]*9 + pm[q][1])*9 + pm[q][2]); ++cnt; }
        }
        D.c3[s] = (unsigned char)cnt; ++s;
      }
  s = 0;
  for (int i = 0; i < 9; ++i)
    for (int j = i; j < 9; ++j) {
      D.b2[s][0] = (unsigned short)(i*9 + j);
      D.b2[s][1] = (unsigned short)(j*9 + i);
      D.c2[s] = (unsigned char)((i == j) ? 1 : 2); ++s;
    }
  return D;
}
static constexpr DecTab DT = make_dectab();

template<int KI>
static __device__ __forceinline__ float monoT(const float* xr) {
  if constexpr (TRI.ord[KI] == 3) return xr[TRI.a[KI]] * xr[TRI.b[KI]] * xr[TRI.c3[KI]];
  else if constexpr (TRI.ord[KI] == 2) return xr[TRI.a[KI]] * xr[TRI.b[KI]];
  else if constexpr (TRI.ord[KI] == 1) return xr[TRI.a[KI]];
  else return 0.f;
}

template<int K0>
static __device__ __forceinline__ void mono8(const float* xr, float m[8]) {
  m[0]=monoT<K0+0>(xr); m[1]=monoT<K0+1>(xr); m[2]=monoT<K0+2>(xr); m[3]=monoT<K0+3>(xr);
  m[4]=monoT<K0+4>(xr); m[5]=monoT<K0+5>(xr); m[6]=monoT<K0+6>(xr); m[7]=monoT<K0+7>(xr);
}

template<int T>
static __device__ __forceinline__ void k_steps(const float* xr, const unsigned int* lds_b,
                                               int lane, int ks, f32x16& acc) {
  if constexpr (T < NSTEP) {
    float m[8];
    if (ks == 0) mono8<T*16>(xr, m);
    else         mono8<T*16 + 8>(xr, m);
    short8 mf;
    mf[0]=bf16b(m[0]); mf[1]=bf16b(m[1]); mf[2]=bf16b(m[2]); mf[3]=bf16b(m[3]);
    mf[4]=bf16b(m[4]); mf[5]=bf16b(m[5]); mf[6]=bf16b(m[6]); mf[7]=bf16b(m[7]);
    short8 cf = *(const short8*)&lds_b[(T*64 + lane)*4];
    acc = __builtin_amdgcn_mfma_f32_32x32x16_bf16(cf, mf, acc, 0, 0, 0);
    k_steps<T+1>(xr, lds_b, lane, ks, acc);
  }
}

// ---- build kernel ----
static __device__ __forceinline__ float coefval(int k, int col,
    const float* U1_0, const float* U2_0, const float* U3_0,
    const float* U1_1, const float* U2_1, const float* U3_1) {
  if (k < 165) {
    if (col < 12 || col >= 24) return 0.f;
    int mp = (col - 12) / 3, p = (col - 12) % 3;
    float acc = 0.f;
    int cnt = DT.c3[k];
    for (int q = 0; q < cnt; ++q) {
      int base = DT.b3[k][q];
      acc += (mp == 0) ? U3_0[base*3 + p] : U3_1[base*9 + (mp-1)*3 + p];
    }
    return acc;
  } else if (k < 210) {
    if (col < 4 || col >= 12) return 0.f;
    int mp = (col - 4) / 2, p = (col - 4) % 2;
    int s2 = k - 165;
    float acc = 0.f;
    int cnt = DT.c2[s2];
    for (int q = 0; q < cnt; ++q) {
      int base = DT.b2[s2][q];
      acc += (mp == 0) ? U2_0[base*2 + p] : U2_1[(base*3 + (mp-1))*2 + p];
    }
    return acc;
  } else if (k < 219) {
    int i = k - 210;
    if (col == 0) return U1_0[i];
    if (col < 4) return U1_1[i*3 + (col-1)];
    return 0.f;
  }
  return 0.f;
}

__global__ __launch_bounds__(64) void build_tables_kernel(
    const float* __restrict__ U1_0, const float* __restrict__ U2_0, const float* __restrict__ U3_0,
    const float* __restrict__ U1_1, const float* __restrict__ U2_1, const float* __restrict__ U3_1,
    const float* __restrict__ Wl0, const float* __restrict__ Wl1,
    unsigned int* __restrict__ tbl) {
  const int b = blockIdx.x, l = threadIdx.x;
  const int col = l & 31, ks = l >> 5;
  if (b < NSTEP) {
    const int ft = b;
    #pragma unroll
    for (int d = 0; d < 4; ++d) {
      int k = ft*16 + ks*8 + d*2;
      unsigned short lo = (unsigned short)bf16b(coefval(k,   col, U1_0,U2_0,U3_0,U1_1,U2_1,U3_1));
      unsigned short hi = (unsigned short)bf16b(coefval(k+1, col, U1_0,U2_0,U3_0,U1_1,U2_1,U3_1));
      tbl[(ft*64 + l)*4 + d] = ((unsigned int)hi << 16) | lo;
    }
  } else {
    const int u = b - NSTEP;            // 0..63 : (g, ntile, step)
    const int g = u >> 5, u5 = u & 31, nt = u5 >> 3, st = u5 & 7;
    const float* W = g ? Wl1 : Wl0;     // [c][d] row-major; k = c
    #pragma unroll
    for (int d = 0; d < 4; ++d) {
      int k = st*16 + ks*8 + 2*d;
      unsigned short lo = (unsigned short)bf16b(W[(long)k*128     + nt*32 + col]);
      unsigned short hi = (unsigned short)bf16b(W[(long)(k+1)*128 + nt*32 + col]);
      tbl[WL_OFF + u*256 + l*4 + d] = ((unsigned int)hi << 16) | lo;
    }
  }
}

// ---- main kernel ----
__global__ __launch_bounds__(512, 4) void epbb_mfma_kernel(
    const float* __restrict__ xg,    // [N,128,9]
    const float* __restrict__ na,    // [N,10] one-hot
    const float* __restrict__ sc,    // [N,512]
    const float* __restrict__ W1_0, const float* __restrict__ W2_0, const float* __restrict__ W3_0,
    const float* __restrict__ W1_1, const float* __restrict__ W2_1, const float* __restrict__ W3_1,
    const unsigned int* __restrict__ tbl,
    float* __restrict__ out) {
  __shared__ __align__(16) unsigned int lds_b[TBLB_DWORDS];  // 14336 B
  __shared__ __align__(16) float lds_x[2*128*9];             // 9216 B
  __shared__ __align__(16) short lds_yA[2][8][136];          // 4352 B, 272B row stride
  __shared__ __align__(16) float lds_out[2*512];             // 4096 B

  const int tid  = threadIdx.x;
  const int lane = tid & 63;
  const int w    = tid >> 6;          // wave 0..7
  const int ks   = lane >> 5;
  const int n0   = blockIdx.x * 2;

  // coalesced staging: coef frags (3584 dwords) + x (576 float4)
  for (int q = tid; q < TBLB_DWORDS; q += 512) lds_b[q] = tbl[q];
  {
    const float4* xg4 = (const float4*)(xg + (long)n0*1152);
    float4* lx4 = (float4*)lds_x;
    #pragma unroll
    for (int q = tid; q < 576; q += 512) lx4[q] = xg4[q];
  }

  // this wave: node nw, channels c0..c0+31; lane owns channel cl
  const int nw = w >> 2;
  const int n  = n0 + nw;
  const int c0 = (w & 3) * 32;
  const int cl = c0 + (lane & 31);

  // species (exact one-hot, wave-uniform)
  int e = 0;
  #pragma unroll
  for (int q = 0; q < 10; ++q) e = (na[(long)n*10 + q] > 0.5f) ? q : e;

  // per-(element,channel) path weights issued early (hide L2 latency)
  const float w10  = W1_0[e*128 + cl];
  const float w20a = W2_0[(e*2+0)*128 + cl], w20b = W2_0[(e*2+1)*128 + cl];
  const float w30a = W3_0[(e*3+0)*128 + cl], w30b = W3_0[(e*3+1)*128 + cl], w30c = W3_0[(e*3+2)*128 + cl];
  const float w11  = W1_1[e*128 + cl];
  const float w21a = W2_1[(e*2+0)*128 + cl], w21b = W2_1[(e*2+1)*128 + cl];
  const float w31a = W3_1[(e*3+0)*128 + cl], w31b = W3_1[(e*3+1)*128 + cl], w31c = W3_1[(e*3+2)*128 + cl];

  __syncthreads();   // lds_b + lds_x ready

  // x from LDS: stride-9 dwords, gcd(9,32)=1 -> conflict-free; ks halves broadcast
  float xr[9];
  {
    const float* myx = lds_x + (nw*128 + cl)*9;
    #pragma unroll
    for (int q = 0; q < 9; ++q) xr[q] = myx[q];
  }

  f32x16 acc;
  #pragma unroll
  for (int q = 0; q < 16; ++q) acc[q] = 0.f;

  k_steps<0>(xr, lds_b, lane, ks, acc);

  // ---- phase 2: in-register weighted path reduction ----
  // D[pc][ch]: lane holds ch=lane&31, path-col rr=(r&3)+8*(r>>2)+4*ks at reg r.
  float p0, p1, p2, p3;
  if (ks == 0) {
    p0 = w10*acc[0];
    p1 = w11*acc[1] + w31b*acc[8]  + w31c*acc[9];
    p2 = w11*acc[2] + w21a*acc[4]  + w21b*acc[5] + w31a*acc[10] + w31b*acc[11];
    p3 = w11*acc[3] + w21a*acc[6]  + w21b*acc[7];
  } else {
    p0 = w20a*acc[0] + w20b*acc[1] + w30a*acc[4] + w30b*acc[5] + w30c*acc[6];
    p1 = w21a*acc[2] + w21b*acc[3] + w31a*acc[7];
    p2 = w31c*acc[8];
    p3 = w31a*acc[9] + w31b*acc[10] + w31c*acc[11];
  }
  const float y0 = p0 + __shfl_xor(p0, 32, 64);
  const float y1 = p1 + __shfl_xor(p1, 32, 64);
  const float y2 = p2 + __shfl_xor(p2, 32, 64);
  const float y3 = p3 + __shfl_xor(p3, 32, 64);

  // stage y (bf16) into padded A-tile: g0 rows {nv}, g1 rows {(mp-1)*2+nv}
  if (ks == 0) {
    lds_yA[0][nw][cl]     = bf16b(y0);       // mp=0
    lds_yA[1][nw][cl]     = bf16b(y1);       // mp=1 -> row nv
  } else {
    lds_yA[1][2 + nw][cl] = bf16b(y2);       // mp=2 -> row 2+nv
    lds_yA[1][4 + nw][cl] = bf16b(y3);       // mp=3 -> row 4+nv
  }
  __syncthreads();

  // ---- phase 3: z = y * Wlin via padded MFMA (wave -> (g, ntile)) ----
  const int g  = w >> 2;
  const int nt = w & 3;
  f32x16 z;
  #pragma unroll
  for (int q = 0; q < 16; ++q) z[q] = 0.f;
  const unsigned int* bw = tbl + WL_OFF + ((g*4 + nt)*8)*256;
  #pragma unroll
  for (int st = 0; st < 8; ++st) {
    short8 af = *(const short8*)&lds_yA[g][lane & 7][st*16 + ks*8];  // rows>=8 wrap: broadcast
    short8 bf = *(const short8*)&bw[st*256 + lane*4];
    z = __builtin_amdgcn_mfma_f32_32x32x16_bf16(af, bf, z, 0, 0, 0);
  }
  const float inv = 0.088388347648318447f;   // 1/sqrt(128)
  const int d = nt*32 + (lane & 31);
  // z rows -> lds_out (stride-3 writes conflict-free: gcd(3,32)=1)
  if (g == 0) {
    if (ks == 0) {
      lds_out[0*512 + d] = z[0]*inv;
      lds_out[1*512 + d] = z[1]*inv;
    }
  } else {
    if (ks == 0) {
      lds_out[0*512 + 128 + 3*d + 0] = z[0]*inv;
      lds_out[1*512 + 128 + 3*d + 0] = z[1]*inv;
      lds_out[0*512 + 128 + 3*d + 1] = z[2]*inv;
      lds_out[1*512 + 128 + 3*d + 1] = z[3]*inv;
    } else {
      lds_out[0*512 + 128 + 3*d + 2] = z[0]*inv;   // reg rr=4 -> r=0 at ks=1
      lds_out[1*512 + 128 + 3*d + 2] = z[1]*inv;   // reg rr=5 -> r=1
    }
  }
  __syncthreads();

  // coalesced epilogue: 256 float4 = 2 nodes x 512 f32, fused +sc
  if (tid < 256) {
    float4 v = ((const float4*)lds_out)[tid];
    float4 s = *(const float4*)(sc + (long)n0*512 + tid*4);
    v.x += s.x; v.y += s.y; v.z += s.z; v.w += s.w;
    *(float4*)(out + (long)n0*512 + tid*4) = v;
  }
}

extern "C" void kernel_launch(void* const* d_in, const int* in_sizes, int n_in,
                              void* d_out, int out_size, void* d_ws, size_t ws_size,
                              hipStream_t stream) {
  const float* xg   = (const float*)d_in[0];   // node_feats [N,128,9]
  const float* na   = (const float*)d_in[1];   // node_attrs [N,10]
  const float* sc   = (const float*)d_in[2];   // sc [N,512]
  const float* U1_0 = (const float*)d_in[3];
  const float* W1_0 = (const float*)d_in[4];
  const float* U2_0 = (const float*)d_in[5];
  const float* W2_0 = (const float*)d_in[6];
  const float* U3_0 = (const float*)d_in[7];
  const float* W3_0 = (const float*)d_in[8];
  const float* Wl0  = (const float*)d_in[9];
  const float* U1_1 = (const float*)d_in[10];
  const float* W1_1 = (const float*)d_in[11];
  const float* U2_1 = (const float*)d_in[12];
  const float* W2_1 = (const float*)d_in[13];
  const float* U3_1 = (const float*)d_in[14];
  const float* W3_1 = (const float*)d_in[15];
  const float* Wl1  = (const float*)d_in[16];

  unsigned int* tbl = (unsigned int*)d_ws;     // (3584 + 16384) dwords = 79872 B
  const int N = in_sizes[0] / (128 * 9);

  hipLaunchKernelGGL(build_tables_kernel, dim3(NSTEP + 64), dim3(64), 0, stream,
                     U1_0, U2_0, U3_0, U1_1, U2_1, U3_1, Wl0, Wl1, tbl);
  hipLaunchKernelGGL(epbb_mfma_kernel, dim3(N/2), dim3(512), 0, stream,
                     xg, na, sc, W1_0, W2_0, W3_0, W1_1, W2_1, W3_1, tbl,
                     (float*)d_out);
}